// Round 14
// baseline (170.364 us; speedup 1.0000x reference)
//
#include <hip/hip_runtime.h>

static constexpr int IN_F = 256;
static constexpr int OUT_F = 128;
static constexpr int BM = 64, BN = 128, BK = 32;
static constexpr int NT = IN_F / BK;  // 8 K-tiles
static constexpr int GT = 128;        // GEMM block threads (8 ty x 16 tx)

// ---------------------------------------------------------------------------
// Fused kernel. Blocks [0, gemmBlocks): H = X*W + bias.
// 128-thread blocks, BM=64 -> 782 balanced blocks; 8x8 micro-tile (4 b128
// LDS-reads per 64 FMAs -> 67% VALU ceiling vs 45% for 4x8); SINGLE LDS
// buffer (25 KB -> 6 blocks/CU x 2 waves = 12 waves/CU) + register prefetch.
// Blocks >= gemmBlocks: edge-dst histogram + within-node slot into tmp[e].
// ---------------------------------------------------------------------------
__global__ __launch_bounds__(GT) void gemm_hist_kernel(
    const float* __restrict__ X, const float* __restrict__ W,
    const float* __restrict__ bias, float* __restrict__ H, int M,
    const int* __restrict__ dst, int* __restrict__ deg,
    int* __restrict__ tmp, int E, int gemmBlocks) {
  if ((int)blockIdx.x >= gemmBlocks) {
    const int e = ((int)blockIdx.x - gemmBlocks) * GT + (int)threadIdx.x;
    if (e < E) {
      const int s = atomicAdd(&deg[dst[e]], 1);
      if (tmp) tmp[e] = s;
    }
    return;
  }

  __shared__ float As[BK][BM + 4];  // 32 x 68 x 4B = 8704 B
  __shared__ float Bs[BK][BN];      // 32 x 128 x 4B = 16384 B

  const int tid = threadIdx.x;
  const int tx = tid & 15;   // cols tx*4..+3 and 64+tx*4..+3
  const int ty = tid >> 4;   // 0..7 -> rows ty*8..+7
  const int row0 = (int)blockIdx.x * BM;

  // Staging maps (128 threads):
  // A: 64 rows x 32 k = 512 float4 -> 4/thread
  const int ar = tid >> 3;          // 0..15 (+16u)
  const int ac4 = (tid & 7) << 2;   // 0,4,..,28
  // B: 32 k x 128 cols = 1024 float4 -> 8/thread
  const int bk_ = tid >> 5;         // 0..3 (+4u)
  const int bn4 = (tid & 31) << 2;  // 0..124

  float acc[8][8];
#pragma unroll
  for (int i = 0; i < 8; ++i)
#pragma unroll
    for (int j = 0; j < 8; ++j) acc[i][j] = 0.f;

  const float4 fz = make_float4(0.f, 0.f, 0.f, 0.f);

  float4 pA[4];
  float4 pB[8];
  // Prologue: prefetch tile 0 into registers.
#pragma unroll
  for (int u = 0; u < 4; ++u) {
    const int gr = row0 + ar + u * 16;
    pA[u] = (gr < M) ? *(const float4*)(X + (size_t)gr * IN_F + ac4) : fz;
  }
#pragma unroll
  for (int u = 0; u < 8; ++u) {
    pB[u] = *(const float4*)(W + (size_t)(bk_ + u * 4) * OUT_F + bn4);
  }

#pragma unroll 1
  for (int t = 0; t < NT; ++t) {
    // Stage current tile regs -> LDS.
#pragma unroll
    for (int u = 0; u < 4; ++u) {
      const int r = ar + u * 16;
      As[ac4 + 0][r] = pA[u].x;
      As[ac4 + 1][r] = pA[u].y;
      As[ac4 + 2][r] = pA[u].z;
      As[ac4 + 3][r] = pA[u].w;
    }
#pragma unroll
    for (int u = 0; u < 8; ++u) {
      *(float4*)&Bs[bk_ + u * 4][bn4] = pB[u];
    }
    __syncthreads();

    // Prefetch next tile (in flight through the compute phase).
    if (t + 1 < NT) {
      const int k0 = (t + 1) * BK;
#pragma unroll
      for (int u = 0; u < 4; ++u) {
        const int gr = row0 + ar + u * 16;
        pA[u] =
            (gr < M) ? *(const float4*)(X + (size_t)gr * IN_F + k0 + ac4) : fz;
      }
#pragma unroll
      for (int u = 0; u < 8; ++u) {
        pB[u] = *(const float4*)(W + (size_t)(k0 + bk_ + u * 4) * OUT_F + bn4);
      }
    }

    // Compute: 8x8 micro-tile, 4 b128 reads per 64 FMAs.
#pragma unroll
    for (int kk = 0; kk < BK; ++kk) {
      const float4 a0 = *(const float4*)&As[kk][ty * 8];
      const float4 a1 = *(const float4*)&As[kk][ty * 8 + 4];
      const float4 b0 = *(const float4*)&Bs[kk][tx * 4];
      const float4 b1 = *(const float4*)&Bs[kk][64 + tx * 4];
      const float av[8] = {a0.x, a0.y, a0.z, a0.w, a1.x, a1.y, a1.z, a1.w};
#pragma unroll
      for (int i = 0; i < 8; ++i) {
        acc[i][0] = fmaf(av[i], b0.x, acc[i][0]);
        acc[i][1] = fmaf(av[i], b0.y, acc[i][1]);
        acc[i][2] = fmaf(av[i], b0.z, acc[i][2]);
        acc[i][3] = fmaf(av[i], b0.w, acc[i][3]);
        acc[i][4] = fmaf(av[i], b1.x, acc[i][4]);
        acc[i][5] = fmaf(av[i], b1.y, acc[i][5]);
        acc[i][6] = fmaf(av[i], b1.z, acc[i][6]);
        acc[i][7] = fmaf(av[i], b1.w, acc[i][7]);
      }
    }
    __syncthreads();
  }

  float bv0[4], bv1[4];
#pragma unroll
  for (int j = 0; j < 4; ++j) {
    bv0[j] = bias[tx * 4 + j];
    bv1[j] = bias[64 + tx * 4 + j];
  }
#pragma unroll
  for (int i = 0; i < 8; ++i) {
    const int gr = row0 + ty * 8 + i;
    if (gr < M) {
      float4 o0, o1;
      o0.x = acc[i][0] + bv0[0]; o0.y = acc[i][1] + bv0[1];
      o0.z = acc[i][2] + bv0[2]; o0.w = acc[i][3] + bv0[3];
      o1.x = acc[i][4] + bv1[0]; o1.y = acc[i][5] + bv1[1];
      o1.z = acc[i][6] + bv1[2]; o1.w = acc[i][7] + bv1[3];
      *(float4*)(H + (size_t)gr * OUT_F + tx * 4) = o0;
      *(float4*)(H + (size_t)gr * OUT_F + 64 + tx * 4) = o1;
    }
  }
}

// ---------------------------------------------------------------------------
// Hierarchical exclusive scan of deg[n] -> off[n+1]; optional cursor=off copy.
// ---------------------------------------------------------------------------
__global__ __launch_bounds__(256) void scan_partial_kernel(
    const int* __restrict__ deg, int* __restrict__ bsum, int n) {
  __shared__ int red[256];
  const int i = (int)blockIdx.x * 256 + (int)threadIdx.x;
  red[threadIdx.x] = (i < n) ? deg[i] : 0;
  __syncthreads();
  for (int s = 128; s > 0; s >>= 1) {
    if ((int)threadIdx.x < s) red[threadIdx.x] += red[threadIdx.x + s];
    __syncthreads();
  }
  if (threadIdx.x == 0) bsum[blockIdx.x] = red[0];
}

__global__ __launch_bounds__(256) void scan_base_kernel(
    const int* __restrict__ bsum, int* __restrict__ bbase, int nb) {
  __shared__ int sh[256];
  const int t = threadIdx.x;
  const int x = (t < nb) ? bsum[t] : 0;
  sh[t] = x;
  __syncthreads();
  for (int d = 1; d < 256; d <<= 1) {
    const int v = (t >= d) ? sh[t - d] : 0;
    __syncthreads();
    sh[t] += v;
    __syncthreads();
  }
  if (t < nb) bbase[t] = sh[t] - x;  // exclusive
}

__global__ __launch_bounds__(256) void scan_write_kernel(
    const int* __restrict__ deg, const int* __restrict__ bbase,
    int* __restrict__ off, int* __restrict__ cursor, int n) {
  const int i = (int)blockIdx.x * 256 + (int)threadIdx.x;
  const int lane = threadIdx.x & 63;
  const int w = threadIdx.x >> 6;
  const int x = (i < n) ? deg[i] : 0;
  int inc = x;
#pragma unroll
  for (int d = 1; d < 64; d <<= 1) {
    const int t = __shfl_up(inc, d, 64);
    if (lane >= d) inc += t;
  }
  __shared__ int wsum[4];
  if (lane == 63) wsum[w] = inc;
  __syncthreads();
  int wb = 0;
#pragma unroll
  for (int k = 0; k < 4; ++k) wb += (k < w) ? wsum[k] : 0;
  const int excl = bbase[blockIdx.x] + wb + inc - x;
  if (i < n) {
    off[i] = excl;
    if (cursor) cursor[i] = excl;
    if (i == n - 1) off[n] = excl + x;
  }
}

// ---------------------------------------------------------------------------
// Placement (primary, NO atomics): pos = off[dst[e]] + tmp[e].
// ---------------------------------------------------------------------------
__global__ __launch_bounds__(256) void place_kernel(
    const int* __restrict__ dst, const int* __restrict__ src,
    const float* __restrict__ vals, const int* __restrict__ off,
    const int* __restrict__ tmp, int2* __restrict__ pay, int E) {
  const int e = (int)blockIdx.x * 256 + (int)threadIdx.x;
  if (e < E) {
    const int pos = off[dst[e]] + tmp[e];
    pay[pos] = make_int2(src[e], __float_as_int(vals[e]));
  }
}

// Fallback scatters (atomic cursor).
__global__ __launch_bounds__(256) void scatter_pay_kernel(
    const int* __restrict__ dst, const int* __restrict__ src,
    const float* __restrict__ vals, int* __restrict__ cursor,
    int2* __restrict__ pay, int E) {
  const int e = (int)blockIdx.x * 256 + (int)threadIdx.x;
  if (e < E) {
    const int pos = atomicAdd(&cursor[dst[e]], 1);
    pay[pos] = make_int2(src[e], __float_as_int(vals[e]));
  }
}

__global__ __launch_bounds__(256) void scatter_perm_kernel(
    const int* __restrict__ dst, int* __restrict__ cursor,
    int* __restrict__ perm, int E) {
  const int e = (int)blockIdx.x * 256 + (int)threadIdx.x;
  if (e < E) {
    const int pos = atomicAdd(&cursor[dst[e]], 1);
    perm[pos] = e;
  }
}

// ---------------------------------------------------------------------------
// Gather: one 64-lane wave per node; lane-parallel metadata, shfl broadcast,
// 16 independent H-row loads in flight. No fp32 atomics.
// ---------------------------------------------------------------------------
__device__ __forceinline__ float2 h_row2(const float* __restrict__ H, int s,
                                         int lane) {
  return reinterpret_cast<const float2*>(H + (size_t)s * OUT_F)[lane];
}

template <bool PAYLOAD>
__device__ __forceinline__ void gather_body(
    const float* __restrict__ H, const int2* __restrict__ pay,
    const float* __restrict__ vals, const int* __restrict__ src,
    const int* __restrict__ perm, const int* __restrict__ off,
    float* __restrict__ out, int wave, int lane) {
  const int b = off[wave];
  const int e = off[wave + 1];
  float accx = 0.f, accy = 0.f;

  for (int base = b; base < e; base += 64) {
    const int n = min(64, e - base);
    int s = 0;
    float v = 0.f;
    if (lane < n) {
      if (PAYLOAD) {
        const int2 p = pay[base + lane];
        s = p.x;
        v = __int_as_float(p.y);
      } else {
        const int id = perm[base + lane];
        v = vals[id];
        s = src[id];
      }
    }
    int k = 0;
    // 16 independent row loads in flight.
    for (; k + 16 <= n; k += 16) {
      int sj[16];
      float2 hj[16];
      float vj[16];
#pragma unroll
      for (int j = 0; j < 16; ++j) sj[j] = __shfl(s, k + j, 64);
#pragma unroll
      for (int j = 0; j < 16; ++j) hj[j] = h_row2(H, sj[j], lane);
#pragma unroll
      for (int j = 0; j < 16; ++j) vj[j] = __shfl(v, k + j, 64);
#pragma unroll
      for (int j = 0; j < 16; ++j) {
        accx = fmaf(vj[j], hj[j].x, accx);
        accy = fmaf(vj[j], hj[j].y, accy);
      }
    }
    for (; k + 8 <= n; k += 8) {
      int sj[8];
      float2 hj[8];
      float vj[8];
#pragma unroll
      for (int j = 0; j < 8; ++j) sj[j] = __shfl(s, k + j, 64);
#pragma unroll
      for (int j = 0; j < 8; ++j) hj[j] = h_row2(H, sj[j], lane);
#pragma unroll
      for (int j = 0; j < 8; ++j) vj[j] = __shfl(v, k + j, 64);
#pragma unroll
      for (int j = 0; j < 8; ++j) {
        accx = fmaf(vj[j], hj[j].x, accx);
        accy = fmaf(vj[j], hj[j].y, accy);
      }
    }
    for (; k < n; ++k) {
      const int sk = __shfl(s, k, 64);
      const float vk = __shfl(v, k, 64);
      const float2 hv = h_row2(H, sk, lane);
      accx = fmaf(vk, hv.x, accx);
      accy = fmaf(vk, hv.y, accy);
    }
  }
  float2 o;
  o.x = accx;
  o.y = accy;
  reinterpret_cast<float2*>(out + (size_t)wave * OUT_F)[lane] = o;
}

__global__ __launch_bounds__(256) void gather_pay_kernel(
    const float* __restrict__ H, const int2* __restrict__ pay,
    const int* __restrict__ off, float* __restrict__ out, int M) {
  const int wave = (int)((blockIdx.x * blockDim.x + threadIdx.x) >> 6);
  const int lane = threadIdx.x & 63;
  if (wave >= M) return;
  gather_body<true>(H, pay, nullptr, nullptr, nullptr, off, out, wave, lane);
}

__global__ __launch_bounds__(256) void gather_perm_kernel(
    const float* __restrict__ H, const float* __restrict__ vals,
    const int* __restrict__ src, const int* __restrict__ off,
    const int* __restrict__ perm, float* __restrict__ out, int M) {
  const int wave = (int)((blockIdx.x * blockDim.x + threadIdx.x) >> 6);
  const int lane = threadIdx.x & 63;
  if (wave >= M) return;
  gather_body<false>(H, nullptr, vals, src, perm, off, out, wave, lane);
}

// ---------------------------------------------------------------------------
extern "C" void kernel_launch(void* const* d_in, const int* in_sizes, int n_in,
                              void* d_out, int out_size, void* d_ws,
                              size_t ws_size, hipStream_t stream) {
  const float* X = (const float*)d_in[0];        // [M, 256]
  const float* W = (const float*)d_in[1];        // [256, 128]
  const float* bias = (const float*)d_in[2];     // [128]
  const float* adj_vals = (const float*)d_in[3]; // [E]
  const int* edge_src = (const int*)d_in[4];     // [E]
  const int* edge_dst = (const int*)d_in[5];     // [E]
  float* out = (float*)d_out;                    // [M, 128]

  const int M = in_sizes[0] / IN_F;  // 50000
  const int E = in_sizes[3];         // 800000

  char* ws = (char*)d_ws;
  size_t o = 0;
  auto take = [&](size_t bytes) {
    void* p = ws + o;
    o = (o + bytes + 15) & ~(size_t)15;
    return p;
  };
  float* H = (float*)take((size_t)M * OUT_F * sizeof(float));  // 25.6 MB
  int* off = (int*)take((size_t)(M + 1) * sizeof(int));
  int* deg = (int*)take((size_t)M * sizeof(int));
  const int nb = (M + 255) / 256;  // 196 (<= 256)
  const size_t scanb = 2 * (((size_t)nb * sizeof(int) + 15) & ~(size_t)15);

  // Tier select by ws budget (deterministic).
  const size_t base = o;
  const size_t need_primary = base + ((size_t)E + M) * sizeof(int) +
                              (size_t)E * sizeof(int2) + scanb + 64;
  const size_t need_fb1 =
      base + (size_t)M * sizeof(int) + (size_t)E * sizeof(int2) + scanb + 64;
  const int tier = (ws_size == 0 || need_primary <= ws_size) ? 0
                   : (need_fb1 <= ws_size)                   ? 1
                                                             : 2;

  int *tmp = nullptr, *cursor = nullptr, *perm = nullptr;
  int2* pay = nullptr;
  if (tier == 0) {
    tmp = (int*)take((size_t)E * sizeof(int));
    pay = (int2*)take((size_t)E * sizeof(int2));
  } else if (tier == 1) {
    cursor = (int*)take((size_t)M * sizeof(int));
    pay = (int2*)take((size_t)E * sizeof(int2));
  } else {
    cursor = (int*)take((size_t)M * sizeof(int));
    perm = (int*)take((size_t)E * sizeof(int));
  }
  int* bsum = (int*)take((size_t)nb * sizeof(int));
  int* bbase = (int*)take((size_t)nb * sizeof(int));

  hipMemsetAsync(deg, 0, (size_t)M * sizeof(int), stream);

  const int gemmBlocks = (M + BM - 1) / BM;  // 782
  const int histBlocks = (E + GT - 1) / GT;  // 6250
  gemm_hist_kernel<<<gemmBlocks + histBlocks, GT, 0, stream>>>(
      X, W, bias, H, M, edge_dst, deg, tmp, E, gemmBlocks);

  scan_partial_kernel<<<nb, 256, 0, stream>>>(deg, bsum, M);
  scan_base_kernel<<<1, 256, 0, stream>>>(bsum, bbase, nb);
  scan_write_kernel<<<nb, 256, 0, stream>>>(deg, bbase, off, cursor, M);

  const int eb = (E + 255) / 256;
  dim3 gather_grid((M + 3) / 4);  // 4 waves (256 threads) per block
  if (tier == 0) {
    place_kernel<<<eb, 256, 0, stream>>>(edge_dst, edge_src, adj_vals, off,
                                         tmp, pay, E);
    gather_pay_kernel<<<gather_grid, 256, 0, stream>>>(H, pay, off, out, M);
  } else if (tier == 1) {
    scatter_pay_kernel<<<eb, 256, 0, stream>>>(edge_dst, edge_src, adj_vals,
                                               cursor, pay, E);
    gather_pay_kernel<<<gather_grid, 256, 0, stream>>>(H, pay, off, out, M);
  } else {
    scatter_perm_kernel<<<eb, 256, 0, stream>>>(edge_dst, cursor, perm, E);
    gather_perm_kernel<<<gather_grid, 256, 0, stream>>>(H, adj_vals, edge_src,
                                                        off, perm, out, M);
  }
}

// Round 15
// 138.933 us; speedup vs baseline: 1.2262x; 1.2262x over previous
//
#include <hip/hip_runtime.h>

static constexpr int IN_F = 256;
static constexpr int OUT_F = 128;
static constexpr int BM = 64, BK = 32;
static constexpr int NTK = IN_F / BK;  // 8 K-tiles

using bf16x4 = __attribute__((ext_vector_type(4))) __bf16;
using bf16x8 = __attribute__((ext_vector_type(8))) __bf16;
using f32x4 = __attribute__((ext_vector_type(4))) float;

// k-permutation: fragment split-halves made contiguous.
// kl in [0,32): kp = 8*((kl>>2)&3) + 4*(kl>>4) + (kl&3)
__device__ __host__ __forceinline__ int kperm(int kl) {
  return (((kl >> 2) & 3) << 3) + ((kl >> 4) << 2) + (kl & 3);
}

// ---------------------------------------------------------------------------
// W pre-conversion: W[k][n] fp32 -> WTh/WTl[n][ k-tile*32 + kperm(k%32) ] bf16
// (transposed + fragment-permuted so GEMM staging is plain 16B copies).
// ---------------------------------------------------------------------------
__global__ __launch_bounds__(256) void wconv_kernel(
    const float* __restrict__ W, __bf16* __restrict__ WTh,
    __bf16* __restrict__ WTl) {
  const int idx = (int)blockIdx.x * 256 + (int)threadIdx.x;  // 0..32767
  const int k = idx >> 7;   // 0..255
  const int n = idx & 127;  // 0..127
  const float w = W[idx];
  const __bf16 hi = (__bf16)w;
  const __bf16 lo = (__bf16)(w - (float)hi);
  const int kk = (k & ~31) + kperm(k & 31);
  WTh[n * 256 + kk] = hi;
  WTl[n * 256 + kk] = lo;
}

// ---------------------------------------------------------------------------
// Fused kernel. Blocks [0, gemmBlocks): H = X*W + bias via split-bf16 MFMA:
//   H = Xhi*Whi + Xhi*Wlo + Xlo*Whi   (fp32 accumulate, err ~2^-16 rel)
// mfma_f32_16x16x32_bf16; A row=lane&15, k = {4h+j, 16+4h+j} (h=lane>>4) --
// stored k-permuted so each frag is one ds_read_b128. C/D: col=lane&15,
// row=4h+reg (m89-verified). 4 waves/block; wave w owns D rows 16w..16w+15,
// all 128 cols (8 col-tiles); 24 MFMA per wave per K-tile.
// Blocks >= gemmBlocks: edge-dst histogram + slot into tmp[e] (r13 proven).
// ---------------------------------------------------------------------------
__global__ __launch_bounds__(256) void gemm_hist_kernel(
    const float* __restrict__ X, const __bf16* __restrict__ WTh,
    const __bf16* __restrict__ WTl, const float* __restrict__ bias,
    float* __restrict__ H, int M, const int* __restrict__ dst,
    int* __restrict__ deg, int* __restrict__ tmp, int E, int gemmBlocks) {
  if ((int)blockIdx.x >= gemmBlocks) {
    const int e = ((int)blockIdx.x - gemmBlocks) * 256 + (int)threadIdx.x;
    if (e < E) {
      const int s = atomicAdd(&deg[dst[e]], 1);
      if (tmp) tmp[e] = s;
    }
    return;
  }

  __shared__ __bf16 Ah[64][40], Al[64][40];    // 2 x 5120 B
  __shared__ __bf16 Bh[128][40], Bl[128][40];  // 2 x 10240 B  (total 30720)

  const int tid = threadIdx.x;
  const int wid = tid >> 6;   // wave 0..3 -> D rows 16*wid..+15
  const int lane = tid & 63;
  const int h = lane >> 4;    // 0..3
  const int fr = lane & 15;   // 0..15
  const int row0 = (int)blockIdx.x * BM;

  // A staging map: 2 float4/thread (rows 0..63, k-chunks of 4).
  const int ar = tid >> 3;               // 0..31 (+32)
  const int ac4 = (tid & 7) << 2;        // 0,4,..,28
  const int akp = kperm(ac4);            // permuted k-col for this chunk
  // B staging map: thread covers col=tid>>1, segs {2*(tid&1), 2*(tid&1)+1}.
  const int bcol = tid >> 1;
  const int bseg0 = (tid & 1) << 1;

  f32x4 acc[8];
#pragma unroll
  for (int c = 0; c < 8; ++c) acc[c] = (f32x4){0.f, 0.f, 0.f, 0.f};

  const float4 fz = make_float4(0.f, 0.f, 0.f, 0.f);
  const int gr0 = row0 + ar;
  const int gr1 = row0 + ar + 32;

  // Prologue: prefetch tile 0.
  float4 pA0 = (gr0 < M) ? *(const float4*)(X + (size_t)gr0 * IN_F + ac4) : fz;
  float4 pA1 = (gr1 < M) ? *(const float4*)(X + (size_t)gr1 * IN_F + ac4) : fz;
  bf16x8 pBh0 = *(const bf16x8*)(WTh + bcol * 256 + 8 * bseg0);
  bf16x8 pBh1 = *(const bf16x8*)(WTh + bcol * 256 + 8 * bseg0 + 8);
  bf16x8 pBl0 = *(const bf16x8*)(WTl + bcol * 256 + 8 * bseg0);
  bf16x8 pBl1 = *(const bf16x8*)(WTl + bcol * 256 + 8 * bseg0 + 8);

#pragma unroll 1
  for (int t = 0; t < NTK; ++t) {
    // Stage A (convert fp32 -> hi/lo bf16) and B into LDS.
    {
      float a0[4] = {pA0.x, pA0.y, pA0.z, pA0.w};
      float a1[4] = {pA1.x, pA1.y, pA1.z, pA1.w};
      bf16x4 h0, l0, h1, l1;
#pragma unroll
      for (int j = 0; j < 4; ++j) {
        h0[j] = (__bf16)a0[j];
        l0[j] = (__bf16)(a0[j] - (float)h0[j]);
        h1[j] = (__bf16)a1[j];
        l1[j] = (__bf16)(a1[j] - (float)h1[j]);
      }
      *(bf16x4*)&Ah[ar][akp] = h0;
      *(bf16x4*)&Al[ar][akp] = l0;
      *(bf16x4*)&Ah[ar + 32][akp] = h1;
      *(bf16x4*)&Al[ar + 32][akp] = l1;
      *(bf16x8*)&Bh[bcol][8 * bseg0] = pBh0;
      *(bf16x8*)&Bh[bcol][8 * bseg0 + 8] = pBh1;
      *(bf16x8*)&Bl[bcol][8 * bseg0] = pBl0;
      *(bf16x8*)&Bl[bcol][8 * bseg0 + 8] = pBl1;
    }
    __syncthreads();

    // Prefetch next K-tile (in flight through the MFMA phase).
    if (t + 1 < NTK) {
      const int k0 = (t + 1) * BK;
      pA0 = (gr0 < M) ? *(const float4*)(X + (size_t)gr0 * IN_F + k0 + ac4) : fz;
      pA1 = (gr1 < M) ? *(const float4*)(X + (size_t)gr1 * IN_F + k0 + ac4) : fz;
      pBh0 = *(const bf16x8*)(WTh + bcol * 256 + k0 + 8 * bseg0);
      pBh1 = *(const bf16x8*)(WTh + bcol * 256 + k0 + 8 * bseg0 + 8);
      pBl0 = *(const bf16x8*)(WTl + bcol * 256 + k0 + 8 * bseg0);
      pBl1 = *(const bf16x8*)(WTl + bcol * 256 + k0 + 8 * bseg0 + 8);
    }

    // Compute: per wave, A frags once, then 8 col-tiles x 3 MFMA.
    const bf16x8 fah = *(const bf16x8*)&Ah[16 * wid + fr][8 * h];
    const bf16x8 fal = *(const bf16x8*)&Al[16 * wid + fr][8 * h];
#pragma unroll
    for (int ct = 0; ct < 8; ++ct) {
      const bf16x8 fbh = *(const bf16x8*)&Bh[ct * 16 + fr][8 * h];
      const bf16x8 fbl = *(const bf16x8*)&Bl[ct * 16 + fr][8 * h];
      acc[ct] =
          __builtin_amdgcn_mfma_f32_16x16x32_bf16(fah, fbh, acc[ct], 0, 0, 0);
      acc[ct] =
          __builtin_amdgcn_mfma_f32_16x16x32_bf16(fah, fbl, acc[ct], 0, 0, 0);
      acc[ct] =
          __builtin_amdgcn_mfma_f32_16x16x32_bf16(fal, fbh, acc[ct], 0, 0, 0);
    }
    __syncthreads();
  }

  // Epilogue: D col = lane&15, row = 4h + reg (per 16x16 tile).
  const int rbase = row0 + 16 * wid + 4 * h;
#pragma unroll
  for (int ct = 0; ct < 8; ++ct) {
    const int col = ct * 16 + fr;
    const float bv = bias[col];
#pragma unroll
    for (int r = 0; r < 4; ++r) {
      const int gr = rbase + r;
      if (gr < M) H[(size_t)gr * OUT_F + col] = acc[ct][r] + bv;
    }
  }
}

// ---------------------------------------------------------------------------
// Hierarchical exclusive scan of deg[n] -> off[n+1]; optional cursor=off copy.
// ---------------------------------------------------------------------------
__global__ __launch_bounds__(256) void scan_partial_kernel(
    const int* __restrict__ deg, int* __restrict__ bsum, int n) {
  __shared__ int red[256];
  const int i = (int)blockIdx.x * 256 + (int)threadIdx.x;
  red[threadIdx.x] = (i < n) ? deg[i] : 0;
  __syncthreads();
  for (int s = 128; s > 0; s >>= 1) {
    if ((int)threadIdx.x < s) red[threadIdx.x] += red[threadIdx.x + s];
    __syncthreads();
  }
  if (threadIdx.x == 0) bsum[blockIdx.x] = red[0];
}

__global__ __launch_bounds__(256) void scan_base_kernel(
    const int* __restrict__ bsum, int* __restrict__ bbase, int nb) {
  __shared__ int sh[256];
  const int t = threadIdx.x;
  const int x = (t < nb) ? bsum[t] : 0;
  sh[t] = x;
  __syncthreads();
  for (int d = 1; d < 256; d <<= 1) {
    const int v = (t >= d) ? sh[t - d] : 0;
    __syncthreads();
    sh[t] += v;
    __syncthreads();
  }
  if (t < nb) bbase[t] = sh[t] - x;  // exclusive
}

__global__ __launch_bounds__(256) void scan_write_kernel(
    const int* __restrict__ deg, const int* __restrict__ bbase,
    int* __restrict__ off, int* __restrict__ cursor, int n) {
  const int i = (int)blockIdx.x * 256 + (int)threadIdx.x;
  const int lane = threadIdx.x & 63;
  const int w = threadIdx.x >> 6;
  const int x = (i < n) ? deg[i] : 0;
  int inc = x;
#pragma unroll
  for (int d = 1; d < 64; d <<= 1) {
    const int t = __shfl_up(inc, d, 64);
    if (lane >= d) inc += t;
  }
  __shared__ int wsum[4];
  if (lane == 63) wsum[w] = inc;
  __syncthreads();
  int wb = 0;
#pragma unroll
  for (int k = 0; k < 4; ++k) wb += (k < w) ? wsum[k] : 0;
  const int excl = bbase[blockIdx.x] + wb + inc - x;
  if (i < n) {
    off[i] = excl;
    if (cursor) cursor[i] = excl;
    if (i == n - 1) off[n] = excl + x;
  }
}

// ---------------------------------------------------------------------------
// Placement (primary, NO atomics): pos = off[dst[e]] + tmp[e].
// ---------------------------------------------------------------------------
__global__ __launch_bounds__(256) void place_kernel(
    const int* __restrict__ dst, const int* __restrict__ src,
    const float* __restrict__ vals, const int* __restrict__ off,
    const int* __restrict__ tmp, int2* __restrict__ pay, int E) {
  const int e = (int)blockIdx.x * 256 + (int)threadIdx.x;
  if (e < E) {
    const int pos = off[dst[e]] + tmp[e];
    pay[pos] = make_int2(src[e], __float_as_int(vals[e]));
  }
}

// Fallback scatters (atomic cursor).
__global__ __launch_bounds__(256) void scatter_pay_kernel(
    const int* __restrict__ dst, const int* __restrict__ src,
    const float* __restrict__ vals, int* __restrict__ cursor,
    int2* __restrict__ pay, int E) {
  const int e = (int)blockIdx.x * 256 + (int)threadIdx.x;
  if (e < E) {
    const int pos = atomicAdd(&cursor[dst[e]], 1);
    pay[pos] = make_int2(src[e], __float_as_int(vals[e]));
  }
}

__global__ __launch_bounds__(256) void scatter_perm_kernel(
    const int* __restrict__ dst, int* __restrict__ cursor,
    int* __restrict__ perm, int E) {
  const int e = (int)blockIdx.x * 256 + (int)threadIdx.x;
  if (e < E) {
    const int pos = atomicAdd(&cursor[dst[e]], 1);
    perm[pos] = e;
  }
}

// ---------------------------------------------------------------------------
// Gather: one 64-lane wave per node; lane-parallel metadata, shfl broadcast,
// 16 independent H-row loads in flight. No fp32 atomics.
// ---------------------------------------------------------------------------
__device__ __forceinline__ float2 h_row2(const float* __restrict__ H, int s,
                                         int lane) {
  return reinterpret_cast<const float2*>(H + (size_t)s * OUT_F)[lane];
}

template <bool PAYLOAD>
__device__ __forceinline__ void gather_body(
    const float* __restrict__ H, const int2* __restrict__ pay,
    const float* __restrict__ vals, const int* __restrict__ src,
    const int* __restrict__ perm, const int* __restrict__ off,
    float* __restrict__ out, int wave, int lane) {
  const int b = off[wave];
  const int e = off[wave + 1];
  float accx = 0.f, accy = 0.f;

  for (int base = b; base < e; base += 64) {
    const int n = min(64, e - base);
    int s = 0;
    float v = 0.f;
    if (lane < n) {
      if (PAYLOAD) {
        const int2 p = pay[base + lane];
        s = p.x;
        v = __int_as_float(p.y);
      } else {
        const int id = perm[base + lane];
        v = vals[id];
        s = src[id];
      }
    }
    int k = 0;
    for (; k + 16 <= n; k += 16) {
      int sj[16];
      float2 hj[16];
      float vj[16];
#pragma unroll
      for (int j = 0; j < 16; ++j) sj[j] = __shfl(s, k + j, 64);
#pragma unroll
      for (int j = 0; j < 16; ++j) hj[j] = h_row2(H, sj[j], lane);
#pragma unroll
      for (int j = 0; j < 16; ++j) vj[j] = __shfl(v, k + j, 64);
#pragma unroll
      for (int j = 0; j < 16; ++j) {
        accx = fmaf(vj[j], hj[j].x, accx);
        accy = fmaf(vj[j], hj[j].y, accy);
      }
    }
    for (; k + 8 <= n; k += 8) {
      int sj[8];
      float2 hj[8];
      float vj[8];
#pragma unroll
      for (int j = 0; j < 8; ++j) sj[j] = __shfl(s, k + j, 64);
#pragma unroll
      for (int j = 0; j < 8; ++j) hj[j] = h_row2(H, sj[j], lane);
#pragma unroll
      for (int j = 0; j < 8; ++j) vj[j] = __shfl(v, k + j, 64);
#pragma unroll
      for (int j = 0; j < 8; ++j) {
        accx = fmaf(vj[j], hj[j].x, accx);
        accy = fmaf(vj[j], hj[j].y, accy);
      }
    }
    for (; k < n; ++k) {
      const int sk = __shfl(s, k, 64);
      const float vk = __shfl(v, k, 64);
      const float2 hv = h_row2(H, sk, lane);
      accx = fmaf(vk, hv.x, accx);
      accy = fmaf(vk, hv.y, accy);
    }
  }
  float2 o;
  o.x = accx;
  o.y = accy;
  reinterpret_cast<float2*>(out + (size_t)wave * OUT_F)[lane] = o;
}

__global__ __launch_bounds__(256) void gather_pay_kernel(
    const float* __restrict__ H, const int2* __restrict__ pay,
    const int* __restrict__ off, float* __restrict__ out, int M) {
  const int wave = (int)((blockIdx.x * blockDim.x + threadIdx.x) >> 6);
  const int lane = threadIdx.x & 63;
  if (wave >= M) return;
  gather_body<true>(H, pay, nullptr, nullptr, nullptr, off, out, wave, lane);
}

__global__ __launch_bounds__(256) void gather_perm_kernel(
    const float* __restrict__ H, const float* __restrict__ vals,
    const int* __restrict__ src, const int* __restrict__ off,
    const int* __restrict__ perm, float* __restrict__ out, int M) {
  const int wave = (int)((blockIdx.x * blockDim.x + threadIdx.x) >> 6);
  const int lane = threadIdx.x & 63;
  if (wave >= M) return;
  gather_body<false>(H, nullptr, vals, src, perm, off, out, wave, lane);
}

// ---------------------------------------------------------------------------
extern "C" void kernel_launch(void* const* d_in, const int* in_sizes, int n_in,
                              void* d_out, int out_size, void* d_ws,
                              size_t ws_size, hipStream_t stream) {
  const float* X = (const float*)d_in[0];        // [M, 256]
  const float* W = (const float*)d_in[1];        // [256, 128]
  const float* bias = (const float*)d_in[2];     // [128]
  const float* adj_vals = (const float*)d_in[3]; // [E]
  const int* edge_src = (const int*)d_in[4];     // [E]
  const int* edge_dst = (const int*)d_in[5];     // [E]
  float* out = (float*)d_out;                    // [M, 128]

  const int M = in_sizes[0] / IN_F;  // 50000
  const int E = in_sizes[3];         // 800000

  char* ws = (char*)d_ws;
  size_t o = 0;
  auto take = [&](size_t bytes) {
    void* p = ws + o;
    o = (o + bytes + 15) & ~(size_t)15;
    return p;
  };
  float* H = (float*)take((size_t)M * OUT_F * sizeof(float));  // 25.6 MB
  int* off = (int*)take((size_t)(M + 1) * sizeof(int));
  int* deg = (int*)take((size_t)M * sizeof(int));
  __bf16* WTh = (__bf16*)take((size_t)OUT_F * IN_F * sizeof(__bf16));  // 64 KB
  __bf16* WTl = (__bf16*)take((size_t)OUT_F * IN_F * sizeof(__bf16));  // 64 KB
  const int nb = (M + 255) / 256;  // 196 (<= 256)
  const size_t scanb = 2 * (((size_t)nb * sizeof(int) + 15) & ~(size_t)15);

  // Tier select by ws budget (deterministic).
  const size_t base = o;
  const size_t need_primary = base + ((size_t)E + M) * sizeof(int) +
                              (size_t)E * sizeof(int2) + scanb + 64;
  const size_t need_fb1 =
      base + (size_t)M * sizeof(int) + (size_t)E * sizeof(int2) + scanb + 64;
  const int tier = (ws_size == 0 || need_primary <= ws_size) ? 0
                   : (need_fb1 <= ws_size)                   ? 1
                                                             : 2;

  int *tmp = nullptr, *cursor = nullptr, *perm = nullptr;
  int2* pay = nullptr;
  if (tier == 0) {
    tmp = (int*)take((size_t)E * sizeof(int));
    pay = (int2*)take((size_t)E * sizeof(int2));
  } else if (tier == 1) {
    cursor = (int*)take((size_t)M * sizeof(int));
    pay = (int2*)take((size_t)E * sizeof(int2));
  } else {
    cursor = (int*)take((size_t)M * sizeof(int));
    perm = (int*)take((size_t)E * sizeof(int));
  }
  int* bsum = (int*)take((size_t)nb * sizeof(int));
  int* bbase = (int*)take((size_t)nb * sizeof(int));

  hipMemsetAsync(deg, 0, (size_t)M * sizeof(int), stream);

  wconv_kernel<<<(IN_F * OUT_F) / 256, 256, 0, stream>>>(W, WTh, WTl);

  const int gemmBlocks = (M + BM - 1) / BM;  // 782
  const int histBlocks = (E + 255) / 256;    // 3125
  gemm_hist_kernel<<<gemmBlocks + histBlocks, 256, 0, stream>>>(
      X, WTh, WTl, bias, H, M, edge_dst, deg, tmp, E, gemmBlocks);

  scan_partial_kernel<<<nb, 256, 0, stream>>>(deg, bsum, M);
  scan_base_kernel<<<1, 256, 0, stream>>>(bsum, bbase, nb);
  scan_write_kernel<<<nb, 256, 0, stream>>>(deg, bbase, off, cursor, M);

  const int eb = (E + 255) / 256;
  dim3 gather_grid((M + 3) / 4);  // 4 waves (256 threads) per block
  if (tier == 0) {
    place_kernel<<<eb, 256, 0, stream>>>(edge_dst, edge_src, adj_vals, off,
                                         tmp, pay, E);
    gather_pay_kernel<<<gather_grid, 256, 0, stream>>>(H, pay, off, out, M);
  } else if (tier == 1) {
    scatter_pay_kernel<<<eb, 256, 0, stream>>>(edge_dst, edge_src, adj_vals,
                                               cursor, pay, E);
    gather_pay_kernel<<<gather_grid, 256, 0, stream>>>(H, pay, off, out, M);
  } else {
    scatter_perm_kernel<<<eb, 256, 0, stream>>>(edge_dst, cursor, perm, E);
    gather_perm_kernel<<<gather_grid, 256, 0, stream>>>(H, adj_vals, edge_src,
                                                        off, perm, out, M);
  }
}